// Round 5
// baseline (294.378 us; speedup 1.0000x reference)
//
#include <hip/hip_runtime.h>
#include <hip/hip_bf16.h>
#include <math.h>

// MultiHeadDiffAttention, MI355X. Round 13: counted-vmcnt 3-buffer pipeline.
// R12 post-mortem: branch-split raised occupancy 18->25.7% but dur only
// 127->123us. No pipe >36%, HBM 16%, conflicts ~3cyc/read -> the limiter is
// the 2-phase barrier structure: __syncthreads drains vmcnt(0) every iter,
// serializing prefetch-completion into the critical path (m233: stage+
// vmcnt+barrier can be ~72% of a 2-phase loop). Fix = T3/T4: 3 LDS buffers,
// stage iter t+2 during iter t, s_waitcnt vmcnt(3) lgkmcnt(0) + raw
// s_barrier -> t+2 loads stay in flight across the barrier, loads get 2
// compute-phases of latency cover. LDS 24->36KB (still >=3 blocks/CU;
// register-limited at 3 waves/SIMD, unchanged).
// Keeps: branch-split blocks, S^T scheme, in-register P pack, additive
// no-max softmax partials, fused combine+RMSNorm.
// B=2 S=2048 E=1024 H=8 DH=128 F=64.
// ws layout (64 MB):
//   [Oacc 32MB f32 (xb bf16 overlays head, dead before zero_ws)]
//   [wob 2MB][wqb 2MB <- Lacc overlays after gemm_qkv][wkb 2][wvb 2]
//   [Qb 8MB <- Nb overlays after attn][Kb 8MB][Vtb 8MB]

#define SDIM 2048
#define EDIM 1024
#define HDIM 8
#define DHDIM 128

typedef unsigned short u16;
typedef __attribute__((ext_vector_type(8))) short bf16x8;
typedef __attribute__((ext_vector_type(4))) short bf16x4;
typedef __attribute__((ext_vector_type(4))) u16 u16x4;
typedef __attribute__((ext_vector_type(8))) u16 u16x8;
typedef __attribute__((ext_vector_type(4))) float f32x4;

__device__ __forceinline__ u16 bf16rne(float f) {
    unsigned int u = __float_as_uint(f);
    u += 0x7fff + ((u >> 16) & 1);
    return (u16)(u >> 16);
}

__device__ __forceinline__ void gload16(void* lds, const void* g) {
    __builtin_amdgcn_global_load_lds(
        (const __attribute__((address_space(1))) unsigned int*)g,
        (__attribute__((address_space(3))) unsigned int*)lds, 16, 0, 0);
}

constexpr int GM = 4096, GN = 1024, GK = 1024;

// ------------------------------------------------------------------
// cast fp32 -> bf16: x (4M) + Wq/Wk/Wv/Wo (1M each).
// ------------------------------------------------------------------
__global__ __launch_bounds__(256) void cast_bf16(
    const float* __restrict__ x,  const float* __restrict__ wq,
    const float* __restrict__ wk, const float* __restrict__ wv,
    const float* __restrict__ wo,
    u16* __restrict__ xb,  u16* __restrict__ wqb, u16* __restrict__ wkb,
    u16* __restrict__ wvb, u16* __restrict__ wob)
{
    int bid = blockIdx.x;
    const float* src; u16* dst; int lb;
    if (bid < 2048)      { src = x;  dst = xb;  lb = bid; }
    else if (bid < 2560) { src = wq; dst = wqb; lb = bid - 2048; }
    else if (bid < 3072) { src = wk; dst = wkb; lb = bid - 2560; }
    else if (bid < 3584) { src = wv; dst = wvb; lb = bid - 3072; }
    else                 { src = wo; dst = wob; lb = bid - 3584; }
    size_t i = ((size_t)lb * 256 + threadIdx.x) * 8;
    float4 a = *(const float4*)&src[i];
    float4 b = *(const float4*)&src[i + 4];
    u16x8 o;
    o[0] = bf16rne(a.x); o[1] = bf16rne(a.y); o[2] = bf16rne(a.z); o[3] = bf16rne(a.w);
    o[4] = bf16rne(b.x); o[5] = bf16rne(b.y); o[6] = bf16rne(b.z); o[7] = bf16rne(b.w);
    *(u16x8*)&dst[i] = o;
}

// ------------------------------------------------------------------
// zero Oacc (8.39M f32) + Lacc (64K f32)
// ------------------------------------------------------------------
__global__ __launch_bounds__(256) void zero_ws(
    float* __restrict__ Oacc, float* __restrict__ Lacc)
{
    int bid = blockIdx.x;
    const f32x4 z = (f32x4){0.f, 0.f, 0.f, 0.f};
    if (bid < 8192) {
        *(f32x4*)&Oacc[((size_t)bid * 256 + threadIdx.x) * 4] = z;
    } else {
        *(f32x4*)&Lacc[((size_t)(bid - 8192) * 256 + threadIdx.x) * 4] = z;
    }
}

// ------------------------------------------------------------------
// bf16 MFMA GEMM core: C = A @ W^T, 128x128, BK=32. (unchanged)
// ------------------------------------------------------------------
struct GemmCore {
    f32x4 acc[4][4];
    int m0, n0, wm, wn, ln, quad;
};

__device__ __forceinline__ void gemm_core(
    GemmCore& g, const u16* __restrict__ A, const u16* __restrict__ W,
    u16* AsBase, u16* BsBase)
{
    const int tid = threadIdx.x;
    const int lane = tid & 63;
    const int wv = tid >> 6;
    g.ln = lane & 15; g.quad = lane >> 4;
    g.wm = (wv >> 1) * 64; g.wn = (wv & 1) * 64;
    g.m0 = blockIdx.y * 128; g.n0 = blockIdx.x * 128;

#pragma unroll
    for (int i = 0; i < 4; ++i)
#pragma unroll
        for (int j = 0; j < 4; ++j)
            g.acc[i][j] = (f32x4){0.f, 0.f, 0.f, 0.f};

    const int s0 = tid, s1 = tid + 256;
    const int ar0 = s0 >> 2, ac0 = (((s0 & 3) ^ ((ar0 >> 1) & 3)) * 8);
    const int ar1 = s1 >> 2, ac1 = (((s1 & 3) ^ ((ar1 >> 1) & 3)) * 8);
    const u16* pa0 = A + (size_t)(g.m0 + ar0) * GK + ac0;
    const u16* pa1 = A + (size_t)(g.m0 + ar1) * GK + ac1;
    const u16* pb0 = W + (size_t)(g.n0 + ar0) * GK + ac0;
    const u16* pb1 = W + (size_t)(g.n0 + ar1) * GK + ac1;
    u16* la0 = AsBase + s0 * 8; u16* la1 = AsBase + s1 * 8;
    u16* lb0 = BsBase + s0 * 8; u16* lb1 = BsBase + s1 * 8;

    const int roff = ((g.quad ^ ((g.ln >> 1) & 3)) * 8);

    for (int k0 = 0; k0 < GK; k0 += 32) {
        gload16(la0, pa0 + k0);
        gload16(la1, pa1 + k0);
        gload16(lb0, pb0 + k0);
        gload16(lb1, pb1 + k0);
        __syncthreads();

        bf16x8 af[4], bfr[4];
#pragma unroll
        for (int t = 0; t < 4; ++t) {
            af[t]  = *(const bf16x8*)&AsBase[(g.wm + t * 16 + g.ln) * 32 + roff];
            bfr[t] = *(const bf16x8*)&BsBase[(g.wn + t * 16 + g.ln) * 32 + roff];
        }
#pragma unroll
        for (int i = 0; i < 4; ++i)
#pragma unroll
            for (int j = 0; j < 4; ++j)
                g.acc[i][j] = __builtin_amdgcn_mfma_f32_16x16x32_bf16(
                    af[i], bfr[j], g.acc[i][j], 0, 0, 0);
        __syncthreads();
    }
}

// z=0 -> Qb (bf16, PRE-SCALED by 0.125*log2e), z=1 -> Kb, z=2 -> Vt
__global__ __launch_bounds__(256) void gemm_qkv(
    const u16* __restrict__ A,
    const u16* __restrict__ W0, const u16* __restrict__ W1, const u16* __restrict__ W2,
    u16* __restrict__ Qb, u16* __restrict__ Kb, u16* __restrict__ Vtb)
{
    __shared__ u16 As[128 * 32];
    __shared__ u16 Bs[128 * 32];
    const int z = blockIdx.z;
    const u16* W = (z == 0) ? W0 : ((z == 1) ? W1 : W2);
    GemmCore g;
    gemm_core(g, A, W, As, Bs);

    if (z < 2) {
        const float scl = (z == 0) ? 0.125f * 1.44269504f : 1.0f;
        u16* C = (z == 0) ? Qb : Kb;
#pragma unroll
        for (int i = 0; i < 4; ++i) {
            int rb = g.m0 + g.wm + i * 16 + g.quad * 4;
#pragma unroll
            for (int r = 0; r < 4; ++r) {
                u16* crow = C + (size_t)(rb + r) * GN + g.n0 + g.wn + g.ln;
#pragma unroll
                for (int j = 0; j < 4; ++j)
                    crow[j * 16] = bf16rne(g.acc[i][j][r] * scl);
            }
        }
    } else {
        const int bb = g.m0 >> 11;
        const int sb = (g.m0 & 2047) + g.wm + g.quad * 4;
#pragma unroll
        for (int j = 0; j < 4; ++j) {
            int dhg = g.n0 + g.wn + j * 16 + g.ln;
            int hh = dhg >> 7, dh = dhg & 127;
            u16* vrow = Vtb + ((size_t)(bb * 8 + hh) * DHDIM + dh) * SDIM + sb;
#pragma unroll
            for (int i = 0; i < 4; ++i) {
                u16x4 pk;
#pragma unroll
                for (int r = 0; r < 4; ++r) pk[r] = bf16rne(g.acc[i][j][r]);
                *(u16x4*)&vrow[i * 16] = pk;
            }
        }
    }
}

// out = (A @ W.T + bias) * (1-dw), fp32 output
__global__ __launch_bounds__(256) void gemm_out(
    const u16* __restrict__ A, const u16* __restrict__ W,
    float* __restrict__ C, const float* __restrict__ bias,
    const float* __restrict__ dwp)
{
    __shared__ u16 As[128 * 32];
    __shared__ u16 Bs[128 * 32];
    GemmCore g;
    gemm_core(g, A, W, As, Bs);

    const float scale = 1.0f - dwp[0];
    float bv[4];
#pragma unroll
    for (int j = 0; j < 4; ++j) bv[j] = bias[g.n0 + g.wn + j * 16 + g.ln];
#pragma unroll
    for (int i = 0; i < 4; ++i) {
        int rb = g.m0 + g.wm + i * 16 + g.quad * 4;
#pragma unroll
        for (int r = 0; r < 4; ++r) {
            float* crow = C + (size_t)(rb + r) * GN + g.n0 + g.wn + g.ln;
#pragma unroll
            for (int j = 0; j < 4; ++j)
                crow[j * 16] = (g.acc[i][j][r] + bv[j]) * scale;
        }
    }
}

// ------------------------------------------------------------------
// MFMA diff attention v10: branch-split + 3-buffer counted-vmcnt pipeline.
// Block = 4 waves; wave owns 32 q (2 q-tiles) for ONE branch.
// Grid (16 qt, 16 bh, 4 = br*2+kvpart). 32 iters of BKV=32.
// Stage t+2 during iter t; pre-barrier wait = vmcnt(3) lgkmcnt(0) so the
// 3 in-flight t+2 loads cross the barrier (never drain to 0 mid-loop).
// Ks/Vs 3 buffers = 36KB LDS. acc[qt][dt] = 64 f32 -> ~132 regs total,
// 3 waves/SIMD.
// ------------------------------------------------------------------
#define KBUF 2048   // u16 per K buffer (32 rows x 64 feats)
#define VBUF 4096   // u16 per V buffer (128 rows x 32 kv)

__global__ __launch_bounds__(256, 3) void attn_mfma(
    const u16* __restrict__ Qb, const u16* __restrict__ Kb,
    const u16* __restrict__ Vtb,
    float* __restrict__ Oacc, float* __restrict__ Lacc)
{
    __shared__ u16 Ks[3 * KBUF];   // 3-buf: 32 kv x 64 f per buffer
    __shared__ u16 Vs[3 * VBUF];   // 3-buf: 128 dh x 32 kv per buffer

    const int tid = threadIdx.x;
    const int wv   = tid >> 6;
    const int lane = tid & 63;
    const int ln = lane & 15, quad = lane >> 4;
    const int lx = ln & 7;
    const int vkey = (ln >> 1) & 3;
    const int bh = blockIdx.y, b = bh >> 3, h = bh & 7;
    const int q0 = blockIdx.x * 128 + wv * 32;        // wave's 32 q rows
    const int BR = blockIdx.z & 1;                    // branch 0/1
    const int kvbase = (blockIdx.z >> 1) * 1024;      // 2 kv parts

    // Q B-frags (pre-scaled): [qt][half], branch BR feats BR*64 + half*32 + quad*8
    const size_t qoff = (size_t)b * SDIM * EDIM + h * DHDIM + BR * 64;
    bf16x8 aq[2][2];
#pragma unroll
    for (int qt = 0; qt < 2; ++qt) {
        const u16* qp = Qb + qoff + (size_t)(q0 + qt * 16 + ln) * EDIM + quad * 8;
        aq[qt][0] = *(const bf16x8*)(qp);
        aq[qt][1] = *(const bf16x8*)(qp + 32);
    }

    // staging maps: K row tid>>3, chunk (tid&7)^(row&7) of 8 (64 feats);
    //               V row s>>2, chunk (s&3)^((row>>1)&3)
    const int s0 = tid, s1 = tid + 256;
    const int kr0 = s0 >> 3, kc0 = ((s0 & 7) ^ (kr0 & 7)) * 8;
    const u16* kg0 = Kb + (size_t)(b * SDIM + kvbase + kr0) * EDIM + h * DHDIM + BR * 64 + kc0;
    const int vr0 = s0 >> 2, vc0 = ((s0 & 3) ^ ((vr0 >> 1) & 3)) * 8;
    const int vr1 = s1 >> 2, vc1 = ((s1 & 3) ^ ((vr1 >> 1) & 3)) * 8;
    const u16* vg0 = Vtb + ((size_t)bh * DHDIM + vr0) * SDIM + kvbase + vc0;
    const u16* vg1 = Vtb + ((size_t)bh * DHDIM + vr1) * SDIM + kvbase + vc1;
    u16* ks0 = Ks + s0 * 8;
    u16* vs0 = Vs + s0 * 8; u16* vs1 = Vs + s1 * 8;

    // prologue: stage iter 0 -> buf0, iter 1 -> buf1 (6 loads in flight)
    gload16(ks0, kg0);
    gload16(vs0, vg0); gload16(vs1, vg1);
    kg0 += 32 * EDIM; vg0 += 32; vg1 += 32;
    gload16(ks0 + KBUF, kg0);
    gload16(vs0 + VBUF, vg0); gload16(vs1 + VBUF, vg1);
    kg0 += 32 * EDIM; vg0 += 32; vg1 += 32;
    // wait until <=3 outstanding (iter-0 loads complete), then sync block
    asm volatile("s_waitcnt vmcnt(3)" ::: "memory");
    __builtin_amdgcn_s_barrier();

    f32x4 acc[2][8];                    // [qt][dt], one branch
#pragma unroll
    for (int qt = 0; qt < 2; ++qt)
#pragma unroll
        for (int d = 0; d < 8; ++d)
            acc[qt][d] = (f32x4){0.f, 0.f, 0.f, 0.f};
    float lsum[2] = {0.f, 0.f};
    const f32x4 z4 = (f32x4){0.f, 0.f, 0.f, 0.f};

    int cb = 0;   // buffer holding current iter's tiles
    int sn = 2;   // buffer to stage iter it+2 into

    for (int it = 0; it < 32; ++it) {
        if (it < 30) {     // stage iter it+2 into buf sn
            gload16(ks0 + sn * KBUF, kg0);
            gload16(vs0 + sn * VBUF, vg0);
            gload16(vs1 + sn * VBUF, vg1);
            kg0 += 32 * EDIM; vg0 += 32; vg1 += 32;
        }

        const u16* Kc = Ks + cb * KBUF;
        const u16* Vc = Vs + cb * VBUF;

        // ---- S^T: st[qt][t2]; K frags shared across qt ----
        f32x4 st[2][2];
#pragma unroll
        for (int t2 = 0; t2 < 2; ++t2) {
            const int rb = (t2 * 16 + ln) * 64;
            bf16x8 k0 = *(const bf16x8*)&Kc[rb + ((quad ^ lx) * 8)];
            bf16x8 k1 = *(const bf16x8*)&Kc[rb + (((4 + quad) ^ lx) * 8)];
#pragma unroll
            for (int qt = 0; qt < 2; ++qt) {
                f32x4 s = __builtin_amdgcn_mfma_f32_16x16x32_bf16(k0, aq[qt][0], z4, 0, 0, 0);
                st[qt][t2] = __builtin_amdgcn_mfma_f32_16x16x32_bf16(k1, aq[qt][1], s, 0, 0, 0);
            }
        }

        // ---- exp + lsum + in-register pack into PV A-frags ----
        union { unsigned int u[4]; bf16x8 v; } ap[2];
#pragma unroll
        for (int qt = 0; qt < 2; ++qt) {
            float e0 = exp2f(st[qt][0][0]), e1 = exp2f(st[qt][0][1]);
            float e2 = exp2f(st[qt][0][2]), e3 = exp2f(st[qt][0][3]);
            float f0 = exp2f(st[qt][1][0]), f1 = exp2f(st[qt][1][1]);
            float f2 = exp2f(st[qt][1][2]), f3 = exp2f(st[qt][1][3]);
            lsum[qt] += (e0 + e1) + (e2 + e3) + (f0 + f1) + (f2 + f3);
            ap[qt].u[0] = __builtin_amdgcn_perm(__float_as_uint(e1), __float_as_uint(e0), 0x07060302u);
            ap[qt].u[1] = __builtin_amdgcn_perm(__float_as_uint(e3), __float_as_uint(e2), 0x07060302u);
            ap[qt].u[2] = __builtin_amdgcn_perm(__float_as_uint(f1), __float_as_uint(f0), 0x07060302u);
            ap[qt].u[3] = __builtin_amdgcn_perm(__float_as_uint(f3), __float_as_uint(f2), 0x07060302u);
        }

        // ---- PV: V B-frag shared across qt (2 MFMAs per read) ----
#pragma unroll
        for (int dt = 0; dt < 8; ++dt) {
            const int vb = (dt * 16 + ln) * 32;
            bf16x4 vlo = *(const bf16x4*)&Vc[vb + ((((quad >> 1) + 0) ^ vkey) * 8 + (quad & 1) * 4)];
            bf16x4 vhi = *(const bf16x4*)&Vc[vb + ((((quad >> 1) + 2) ^ vkey) * 8 + (quad & 1) * 4)];
            bf16x8 vf = __builtin_shufflevector(vlo, vhi, 0, 1, 2, 3, 4, 5, 6, 7);
#pragma unroll
            for (int qt = 0; qt < 2; ++qt)
                acc[qt][dt] = __builtin_amdgcn_mfma_f32_16x16x32_bf16(ap[qt].v, vf, acc[qt][dt], 0, 0, 0);
        }

        // ---- end-of-iter sync: keep the t+2 loads in flight ----
        if (it < 31) {
            if (it < 30)
                asm volatile("s_waitcnt vmcnt(3) lgkmcnt(0)" ::: "memory");
            else
                asm volatile("s_waitcnt vmcnt(0) lgkmcnt(0)" ::: "memory");
            __builtin_amdgcn_s_barrier();
        }
        cb = (cb == 2) ? 0 : cb + 1;
        sn = (sn == 2) ? 0 : sn + 1;
    }

    // ---- atomic accumulation of O partials (branch BR slot) ----
#pragma unroll
    for (int qt = 0; qt < 2; ++qt) {
#pragma unroll
        for (int r = 0; r < 4; ++r) {
            size_t row = (size_t)(b * SDIM + q0 + qt * 16 + quad * 4 + r);
            float* o = Oacc + ((row * 8 + h) * 2 + BR) * 128 + ln;
#pragma unroll
            for (int dt = 0; dt < 8; ++dt)
                atomicAdd(o + dt * 16, acc[qt][dt][r]);
        }
    }
    // ---- l: lane owns q=ln within tile; reduce across quads ----
#pragma unroll
    for (int qt = 0; qt < 2; ++qt) {
        float l = lsum[qt];
        l += __shfl_xor(l, 16, 64); l += __shfl_xor(l, 32, 64);
        if (quad == 0)
            atomicAdd(Lacc + (size_t)((b * 8 + h) * 2 + BR) * SDIM + q0 + qt * 16 + ln, l);
    }
}

// ------------------------------------------------------------------
// combine branches + RMSNorm -> bf16 normed. Grid 4096 rows x 256 thr.
// ------------------------------------------------------------------
__global__ __launch_bounds__(256) void rms_combine(
    const float* __restrict__ Oacc, const float* __restrict__ Lacc,
    const float* __restrict__ nw, u16* __restrict__ Nb,
    const float* __restrict__ dwp)
{
    const int row = blockIdx.x;
    const int tid = threadIdx.x;
    const int h = tid >> 5, dh0 = (tid & 31) * 4;
    const int b = row >> 11, q = row & 2047;

    size_t ob = ((size_t)row * 8 + h) * 2 * 128;
    f32x4 a0 = *(const f32x4*)&Oacc[ob + dh0];
    f32x4 a1 = *(const f32x4*)&Oacc[ob + 128 + dh0];
    float l0 = Lacc[(size_t)((b * 8 + h) * 2 + 0) * SDIM + q];
    float l1 = Lacc[(size_t)((b * 8 + h) * 2 + 1) * SDIM + q];
    const float dw = dwp[0];
    float inv0 = 1.0f / l0;
    float inv1 = dw / l1;
    float o[4];
#pragma unroll
    for (int k = 0; k < 4; ++k) o[k] = a0[k] * inv0 - a1[k] * inv1;

    float ss = o[0] * o[0] + o[1] * o[1] + o[2] * o[2] + o[3] * o[3];
    ss += __shfl_xor(ss, 1,  64);
    ss += __shfl_xor(ss, 2,  64);
    ss += __shfl_xor(ss, 4,  64);
    ss += __shfl_xor(ss, 8,  64);
    ss += __shfl_xor(ss, 16, 64);
    ss += __shfl_xor(ss, 32, 64);
    __shared__ float red[4];
    if ((tid & 63) == 0) red[tid >> 6] = ss;
    __syncthreads();
    float tot = red[0] + red[1] + red[2] + red[3];
    float rms = rsqrtf(tot * (1.0f / 1024.0f) + 1.1920929e-07f);

    float4 w = *(const float4*)&nw[tid * 4];
    u16x4 pk;
    pk[0] = bf16rne(o[0] * rms * w.x);
    pk[1] = bf16rne(o[1] * rms * w.y);
    pk[2] = bf16rne(o[2] * rms * w.z);
    pk[3] = bf16rne(o[3] * rms * w.w);
    *(u16x4*)&Nb[(size_t)row * EDIM + tid * 4] = pk;
}

// ------------------------------------------------------------------
extern "C" void kernel_launch(void* const* d_in, const int* in_sizes, int n_in,
                              void* d_out, int out_size, void* d_ws, size_t ws_size,
                              hipStream_t stream)
{
    const float* x   = (const float*)d_in[0];
    const float* Wq  = (const float*)d_in[1];
    const float* Wk  = (const float*)d_in[2];
    const float* Wv  = (const float*)d_in[3];
    const float* nw  = (const float*)d_in[4];
    const float* Wo  = (const float*)d_in[5];
    const float* bo  = (const float*)d_in[6];
    const float* dwp = (const float*)d_in[7];
    float* out = (float*)d_out;

    float* Oacc = (float*)d_ws;                          // 32 MB
    u16*  xb   = (u16*)d_ws;                             // overlays Oacc head
    u16*  wob  = (u16*)((char*)d_ws + 33554432);         // 2 MB
    u16*  wqb  = wob + 1048576;
    u16*  wkb  = wqb + 1048576;
    u16*  wvb  = wkb + 1048576;
    float* Lacc = (float*)wqb;                           // overlays wqb (dead)
    u16*  Qb   = wvb + 1048576;                          // 8 MB
    u16*  Kb   = Qb + 4194304;
    u16*  Vtb  = Kb + 4194304;
    u16*  Nb   = Qb;                                     // overlays Qb (dead)

    cast_bf16<<<4096, 256, 0, stream>>>(x, Wq, Wk, Wv, Wo,
                                        xb, wqb, wkb, wvb, wob);
    gemm_qkv<<<dim3(GN / 128, GM / 128, 3), 256, 0, stream>>>(
        xb, wqb, wkb, wvb, Qb, Kb, Vtb);
    zero_ws<<<8256, 256, 0, stream>>>(Oacc, Lacc);
    attn_mfma<<<dim3(SDIM / 128, 2 * HDIM, 4), 256, 0, stream>>>(
        Qb, Kb, Vtb, Oacc, Lacc);
    rms_combine<<<4096, 256, 0, stream>>>(Oacc, Lacc, nw, Nb, dwp);
    gemm_out<<<dim3(GN / 128, GM / 128, 1), 256, 0, stream>>>(
        Nb, wob, out, bo, dwp);
}

// Round 7
// 245.183 us; speedup vs baseline: 1.2006x; 1.2006x over previous
//
#include <hip/hip_runtime.h>
#include <hip/hip_bf16.h>
#include <math.h>

// MultiHeadDiffAttention, MI355X. Round 14 (retry; R6 bench was an infra
// "container failed twice" -- source re-audited: store epilogue covers all
// of Oacc exactly once (idempotent under re-runs), uniform barriers, 48KB
// LDS x2 blocks fits, staging maps index-identical to harness-passed R12/13).
// Zero-tail, store-epilogue, KVBLK=64 attention.
// R13 post-mortem: counted-vmcnt pipeline = perfect null vs R12 (123us) ->
// staging latency was never the stall. Quantified losses instead:
// (a) tail: 1024 blocks = 4/CU work, 3 resident -> last round 1/CU (~17%);
// (b) barrier+loop overhead per 32-kv iter; (c) K-read bank conflicts.
// R14: grid (16qt,16bh,2br)=512 blocks = exactly 2/CU zero tail; block owns
// full 2048 kv -> O/L written once -> PLAIN STORES, no atomics, zero_ws
// DELETED. KVBLK=64 (V as 2x32-kv sub-buffers keeps 64B V rows): barriers
// halve, loop overhead halves, 2x independent work per phase. Grid-limited
// 2 waves/SIMD -> regs to 256 free: launch_bounds(256,2).
// Keeps: branch-split, S^T scheme, in-register P pack, additive no-max
// softmax partials, fused combine+RMSNorm.
// B=2 S=2048 E=1024 H=8 DH=128 F=64.
// ws layout (64 MB):
//   [Oacc 32MB f32 (xb bf16 overlays head; attn fully overwrites by STORE)]
//   [wob 2MB][wqb 2MB <- Lacc overlays after gemm_qkv][wkb 2][wvb 2]
//   [Qb 8MB <- Nb overlays after attn][Kb 8MB][Vtb 8MB]

#define SDIM 2048
#define EDIM 1024
#define HDIM 8
#define DHDIM 128

typedef unsigned short u16;
typedef __attribute__((ext_vector_type(8))) short bf16x8;
typedef __attribute__((ext_vector_type(4))) short bf16x4;
typedef __attribute__((ext_vector_type(4))) u16 u16x4;
typedef __attribute__((ext_vector_type(8))) u16 u16x8;
typedef __attribute__((ext_vector_type(4))) float f32x4;

__device__ __forceinline__ u16 bf16rne(float f) {
    unsigned int u = __float_as_uint(f);
    u += 0x7fff + ((u >> 16) & 1);
    return (u16)(u >> 16);
}

__device__ __forceinline__ void gload16(void* lds, const void* g) {
    __builtin_amdgcn_global_load_lds(
        (const __attribute__((address_space(1))) unsigned int*)g,
        (__attribute__((address_space(3))) unsigned int*)lds, 16, 0, 0);
}

constexpr int GM = 4096, GN = 1024, GK = 1024;

// ------------------------------------------------------------------
// cast fp32 -> bf16: x (4M) + Wq/Wk/Wv/Wo (1M each).
// ------------------------------------------------------------------
__global__ __launch_bounds__(256) void cast_bf16(
    const float* __restrict__ x,  const float* __restrict__ wq,
    const float* __restrict__ wk, const float* __restrict__ wv,
    const float* __restrict__ wo,
    u16* __restrict__ xb,  u16* __restrict__ wqb, u16* __restrict__ wkb,
    u16* __restrict__ wvb, u16* __restrict__ wob)
{
    int bid = blockIdx.x;
    const float* src; u16* dst; int lb;
    if (bid < 2048)      { src = x;  dst = xb;  lb = bid; }
    else if (bid < 2560) { src = wq; dst = wqb; lb = bid - 2048; }
    else if (bid < 3072) { src = wk; dst = wkb; lb = bid - 2560; }
    else if (bid < 3584) { src = wv; dst = wvb; lb = bid - 3072; }
    else                 { src = wo; dst = wob; lb = bid - 3584; }
    size_t i = ((size_t)lb * 256 + threadIdx.x) * 8;
    float4 a = *(const float4*)&src[i];
    float4 b = *(const float4*)&src[i + 4];
    u16x8 o;
    o[0] = bf16rne(a.x); o[1] = bf16rne(a.y); o[2] = bf16rne(a.z); o[3] = bf16rne(a.w);
    o[4] = bf16rne(b.x); o[5] = bf16rne(b.y); o[6] = bf16rne(b.z); o[7] = bf16rne(b.w);
    *(u16x8*)&dst[i] = o;
}

// ------------------------------------------------------------------
// bf16 MFMA GEMM core: C = A @ W^T, 128x128, BK=32. (unchanged)
// ------------------------------------------------------------------
struct GemmCore {
    f32x4 acc[4][4];
    int m0, n0, wm, wn, ln, quad;
};

__device__ __forceinline__ void gemm_core(
    GemmCore& g, const u16* __restrict__ A, const u16* __restrict__ W,
    u16* AsBase, u16* BsBase)
{
    const int tid = threadIdx.x;
    const int lane = tid & 63;
    const int wv = tid >> 6;
    g.ln = lane & 15; g.quad = lane >> 4;
    g.wm = (wv >> 1) * 64; g.wn = (wv & 1) * 64;
    g.m0 = blockIdx.y * 128; g.n0 = blockIdx.x * 128;

#pragma unroll
    for (int i = 0; i < 4; ++i)
#pragma unroll
        for (int j = 0; j < 4; ++j)
            g.acc[i][j] = (f32x4){0.f, 0.f, 0.f, 0.f};

    const int s0 = tid, s1 = tid + 256;
    const int ar0 = s0 >> 2, ac0 = (((s0 & 3) ^ ((ar0 >> 1) & 3)) * 8);
    const int ar1 = s1 >> 2, ac1 = (((s1 & 3) ^ ((ar1 >> 1) & 3)) * 8);
    const u16* pa0 = A + (size_t)(g.m0 + ar0) * GK + ac0;
    const u16* pa1 = A + (size_t)(g.m0 + ar1) * GK + ac1;
    const u16* pb0 = W + (size_t)(g.n0 + ar0) * GK + ac0;
    const u16* pb1 = W + (size_t)(g.n0 + ar1) * GK + ac1;
    u16* la0 = AsBase + s0 * 8; u16* la1 = AsBase + s1 * 8;
    u16* lb0 = BsBase + s0 * 8; u16* lb1 = BsBase + s1 * 8;

    const int roff = ((g.quad ^ ((g.ln >> 1) & 3)) * 8);

    for (int k0 = 0; k0 < GK; k0 += 32) {
        gload16(la0, pa0 + k0);
        gload16(la1, pa1 + k0);
        gload16(lb0, pb0 + k0);
        gload16(lb1, pb1 + k0);
        __syncthreads();

        bf16x8 af[4], bfr[4];
#pragma unroll
        for (int t = 0; t < 4; ++t) {
            af[t]  = *(const bf16x8*)&AsBase[(g.wm + t * 16 + g.ln) * 32 + roff];
            bfr[t] = *(const bf16x8*)&BsBase[(g.wn + t * 16 + g.ln) * 32 + roff];
        }
#pragma unroll
        for (int i = 0; i < 4; ++i)
#pragma unroll
            for (int j = 0; j < 4; ++j)
                g.acc[i][j] = __builtin_amdgcn_mfma_f32_16x16x32_bf16(
                    af[i], bfr[j], g.acc[i][j], 0, 0, 0);
        __syncthreads();
    }
}

// z=0 -> Qb (bf16, PRE-SCALED by 0.125*log2e), z=1 -> Kb, z=2 -> Vt
__global__ __launch_bounds__(256) void gemm_qkv(
    const u16* __restrict__ A,
    const u16* __restrict__ W0, const u16* __restrict__ W1, const u16* __restrict__ W2,
    u16* __restrict__ Qb, u16* __restrict__ Kb, u16* __restrict__ Vtb)
{
    __shared__ u16 As[128 * 32];
    __shared__ u16 Bs[128 * 32];
    const int z = blockIdx.z;
    const u16* W = (z == 0) ? W0 : ((z == 1) ? W1 : W2);
    GemmCore g;
    gemm_core(g, A, W, As, Bs);

    if (z < 2) {
        const float scl = (z == 0) ? 0.125f * 1.44269504f : 1.0f;
        u16* C = (z == 0) ? Qb : Kb;
#pragma unroll
        for (int i = 0; i < 4; ++i) {
            int rb = g.m0 + g.wm + i * 16 + g.quad * 4;
#pragma unroll
            for (int r = 0; r < 4; ++r) {
                u16* crow = C + (size_t)(rb + r) * GN + g.n0 + g.wn + g.ln;
#pragma unroll
                for (int j = 0; j < 4; ++j)
                    crow[j * 16] = bf16rne(g.acc[i][j][r] * scl);
            }
        }
    } else {
        const int bb = g.m0 >> 11;
        const int sb = (g.m0 & 2047) + g.wm + g.quad * 4;
#pragma unroll
        for (int j = 0; j < 4; ++j) {
            int dhg = g.n0 + g.wn + j * 16 + g.ln;
            int hh = dhg >> 7, dh = dhg & 127;
            u16* vrow = Vtb + ((size_t)(bb * 8 + hh) * DHDIM + dh) * SDIM + sb;
#pragma unroll
            for (int i = 0; i < 4; ++i) {
                u16x4 pk;
#pragma unroll
                for (int r = 0; r < 4; ++r) pk[r] = bf16rne(g.acc[i][j][r]);
                *(u16x4*)&vrow[i * 16] = pk;
            }
        }
    }
}

// out = (A @ W.T + bias) * (1-dw), fp32 output
__global__ __launch_bounds__(256) void gemm_out(
    const u16* __restrict__ A, const u16* __restrict__ W,
    float* __restrict__ C, const float* __restrict__ bias,
    const float* __restrict__ dwp)
{
    __shared__ u16 As[128 * 32];
    __shared__ u16 Bs[128 * 32];
    GemmCore g;
    gemm_core(g, A, W, As, Bs);

    const float scale = 1.0f - dwp[0];
    float bv[4];
#pragma unroll
    for (int j = 0; j < 4; ++j) bv[j] = bias[g.n0 + g.wn + j * 16 + g.ln];
#pragma unroll
    for (int i = 0; i < 4; ++i) {
        int rb = g.m0 + g.wm + i * 16 + g.quad * 4;
#pragma unroll
        for (int r = 0; r < 4; ++r) {
            float* crow = C + (size_t)(rb + r) * GN + g.n0 + g.wn + g.ln;
#pragma unroll
            for (int j = 0; j < 4; ++j)
                crow[j * 16] = (g.acc[i][j][r] + bv[j]) * scale;
        }
    }
}

// ------------------------------------------------------------------
// MFMA diff attention v11: branch-split, full-kv per block, KVBLK=64.
// Block = 4 waves; wave owns 32 q (2 q-tiles) for ONE branch.
// Grid (16 qt, 16 bh, 2 br) = 512 blocks = 2/CU, zero tail.
// 32 outer iters of 64 kv; dbuf 1-barrier staging (6 gloads/thread/iter).
// K buf: 64 rows x 64 feats (8KB); V: 2 subs x (128 dh x 32 kv) (16KB);
// dbuf total 48KB LDS. Epilogue: plain stores (no atomics, no zeroing).
// ------------------------------------------------------------------
#define KBUF 4096   // u16 per K buffer (64 rows x 64 feats)
#define VBUF 8192   // u16 per V buffer (2 subs x 128 dh x 32 kv)

__global__ __launch_bounds__(256, 2) void attn_mfma(
    const u16* __restrict__ Qb, const u16* __restrict__ Kb,
    const u16* __restrict__ Vtb,
    float* __restrict__ Oacc, float* __restrict__ Lacc)
{
    __shared__ u16 Ks[2 * KBUF];
    __shared__ u16 Vs[2 * VBUF];

    const int tid = threadIdx.x;
    const int wv   = tid >> 6;
    const int lane = tid & 63;
    const int ln = lane & 15, quad = lane >> 4;
    const int lx = ln & 7;
    const int vkey = (ln >> 1) & 3;
    const int bh = blockIdx.y, b = bh >> 3, h = bh & 7;
    const int q0 = blockIdx.x * 128 + wv * 32;        // wave's 32 q rows
    const int BR = blockIdx.z;                        // branch 0/1

    // Q B-frags (pre-scaled): [qt][half], branch BR feats BR*64 + half*32 + quad*8
    const size_t qoff = (size_t)b * SDIM * EDIM + h * DHDIM + BR * 64;
    bf16x8 aq[2][2];
#pragma unroll
    for (int qt = 0; qt < 2; ++qt) {
        const u16* qp = Qb + qoff + (size_t)(q0 + qt * 16 + ln) * EDIM + quad * 8;
        aq[qt][0] = *(const bf16x8*)(qp);
        aq[qt][1] = *(const bf16x8*)(qp + 32);
    }

    // staging maps.
    // K: slot s (16B) -> row s>>3 (0..63), chunk ((s&7)^(row&7)) of 8.
    // V per 32-kv sub: slot s -> row s>>2 (0..127), chunk ((s&3)^((row>>1)&3)).
    const int s0 = tid, s1 = tid + 256;
    const int kr0 = s0 >> 3, kc0 = ((s0 & 7) ^ (kr0 & 7)) * 8;
    const int kr1 = s1 >> 3, kc1 = ((s1 & 7) ^ (kr1 & 7)) * 8;
    const u16* kg0 = Kb + (size_t)(b * SDIM + kr0) * EDIM + h * DHDIM + BR * 64 + kc0;
    const u16* kg1 = Kb + (size_t)(b * SDIM + kr1) * EDIM + h * DHDIM + BR * 64 + kc1;
    const int vr0 = s0 >> 2, vc0 = ((s0 & 3) ^ ((vr0 >> 1) & 3)) * 8;
    const int vr1 = s1 >> 2, vc1 = ((s1 & 3) ^ ((vr1 >> 1) & 3)) * 8;
    const u16* vg0 = Vtb + ((size_t)bh * DHDIM + vr0) * SDIM + vc0;
    const u16* vg1 = Vtb + ((size_t)bh * DHDIM + vr1) * SDIM + vc1;
    u16* ksd0 = Ks + s0 * 8; u16* ksd1 = Ks + s1 * 8;
    u16* vsd0 = Vs + s0 * 8; u16* vsd1 = Vs + s1 * 8;

    // prologue: stage iter 0 into buffer 0 (kv 0..63)
    gload16(ksd0, kg0); gload16(ksd1, kg1);
    gload16(vsd0, vg0); gload16(vsd1, vg1);
    gload16(vsd0 + 4096, vg0 + 32); gload16(vsd1 + 4096, vg1 + 32);
    kg0 += 64 * EDIM; kg1 += 64 * EDIM; vg0 += 64; vg1 += 64;

    f32x4 acc[2][8];                    // [qt][dt], one branch
#pragma unroll
    for (int qt = 0; qt < 2; ++qt)
#pragma unroll
        for (int d = 0; d < 8; ++d)
            acc[qt][d] = (f32x4){0.f, 0.f, 0.f, 0.f};
    float lsum[2] = {0.f, 0.f};
    const f32x4 z4 = (f32x4){0.f, 0.f, 0.f, 0.f};

    for (int it = 0; it < 32; ++it) {
        const int cur = it & 1;
        __syncthreads();   // buf[cur] loads complete; all waves done with buf[cur^1]

        if (it < 31) {     // prefetch iter it+1 into the other buffer
            const int kb = (cur ^ 1) * KBUF, vb2 = (cur ^ 1) * VBUF;
            gload16(ksd0 + kb, kg0); gload16(ksd1 + kb, kg1);
            gload16(vsd0 + vb2, vg0); gload16(vsd1 + vb2, vg1);
            gload16(vsd0 + vb2 + 4096, vg0 + 32); gload16(vsd1 + vb2 + 4096, vg1 + 32);
            kg0 += 64 * EDIM; kg1 += 64 * EDIM; vg0 += 64; vg1 += 64;
        }

        const u16* Kc = Ks + cur * KBUF;
        const u16* Vc = Vs + cur * VBUF;

        // ---- S^T over 64 kv: st[qt][t2], t2 = kv-16-block 0..3 ----
        f32x4 st[2][4];
#pragma unroll
        for (int t2 = 0; t2 < 4; ++t2) {
            const int rb = (t2 * 16 + ln) * 64;
            bf16x8 k0 = *(const bf16x8*)&Kc[rb + ((quad ^ lx) * 8)];
            bf16x8 k1 = *(const bf16x8*)&Kc[rb + (((4 + quad) ^ lx) * 8)];
#pragma unroll
            for (int qt = 0; qt < 2; ++qt) {
                f32x4 s = __builtin_amdgcn_mfma_f32_16x16x32_bf16(k0, aq[qt][0], z4, 0, 0, 0);
                st[qt][t2] = __builtin_amdgcn_mfma_f32_16x16x32_bf16(k1, aq[qt][1], s, 0, 0, 0);
            }
        }

        // ---- exp + lsum + in-register pack: ap[qt][ks] (ks = kv-32-half) ----
        union { unsigned int u[4]; bf16x8 v; } ap[2][2];
#pragma unroll
        for (int qt = 0; qt < 2; ++qt)
#pragma unroll
            for (int ks = 0; ks < 2; ++ks) {
                float e0 = exp2f(st[qt][2 * ks][0]), e1 = exp2f(st[qt][2 * ks][1]);
                float e2 = exp2f(st[qt][2 * ks][2]), e3 = exp2f(st[qt][2 * ks][3]);
                float f0 = exp2f(st[qt][2 * ks + 1][0]), f1 = exp2f(st[qt][2 * ks + 1][1]);
                float f2 = exp2f(st[qt][2 * ks + 1][2]), f3 = exp2f(st[qt][2 * ks + 1][3]);
                lsum[qt] += (e0 + e1) + (e2 + e3) + (f0 + f1) + (f2 + f3);
                ap[qt][ks].u[0] = __builtin_amdgcn_perm(__float_as_uint(e1), __float_as_uint(e0), 0x07060302u);
                ap[qt][ks].u[1] = __builtin_amdgcn_perm(__float_as_uint(e3), __float_as_uint(e2), 0x07060302u);
                ap[qt][ks].u[2] = __builtin_amdgcn_perm(__float_as_uint(f1), __float_as_uint(f0), 0x07060302u);
                ap[qt][ks].u[3] = __builtin_amdgcn_perm(__float_as_uint(f3), __float_as_uint(f2), 0x07060302u);
            }

        // ---- PV: per dt, both kv-32 subs; V B-frag shared across qt ----
#pragma unroll
        for (int dt = 0; dt < 8; ++dt) {
            const int vb = (dt * 16 + ln) * 32;
#pragma unroll
            for (int ks = 0; ks < 2; ++ks) {
                const u16* Vk = Vc + ks * 4096;
                bf16x4 vlo = *(const bf16x4*)&Vk[vb + ((((quad >> 1) + 0) ^ vkey) * 8 + (quad & 1) * 4)];
                bf16x4 vhi = *(const bf16x4*)&Vk[vb + ((((quad >> 1) + 2) ^ vkey) * 8 + (quad & 1) * 4)];
                bf16x8 vf = __builtin_shufflevector(vlo, vhi, 0, 1, 2, 3, 4, 5, 6, 7);
#pragma unroll
                for (int qt = 0; qt < 2; ++qt)
                    acc[qt][dt] = __builtin_amdgcn_mfma_f32_16x16x32_bf16(ap[qt][ks].v, vf, acc[qt][dt], 0, 0, 0);
            }
        }
    }

    // ---- epilogue: plain stores (sole writer of branch-BR slots) ----
#pragma unroll
    for (int qt = 0; qt < 2; ++qt) {
#pragma unroll
        for (int r = 0; r < 4; ++r) {
            size_t row = (size_t)(b * SDIM + q0 + qt * 16 + quad * 4 + r);
            float* o = Oacc + ((row * 8 + h) * 2 + BR) * 128 + ln;
#pragma unroll
            for (int dt = 0; dt < 8; ++dt)
                o[dt * 16] = acc[qt][dt][r];
        }
    }
    // ---- l: lane owns q=ln within tile; reduce across quads; store ----
#pragma unroll
    for (int qt = 0; qt < 2; ++qt) {
        float l = lsum[qt];
        l += __shfl_xor(l, 16, 64); l += __shfl_xor(l, 32, 64);
        if (quad == 0)
            Lacc[(size_t)((b * 8 + h) * 2 + BR) * SDIM + q0 + qt * 16 + ln] = l;
    }
}

// ------------------------------------------------------------------
// combine branches + RMSNorm -> bf16 normed. Grid 4096 rows x 256 thr.
// ------------------------------------------------------------------
__global__ __launch_bounds__(256) void rms_combine(
    const float* __restrict__ Oacc, const float* __restrict__ Lacc,
    const float* __restrict__ nw, u16* __restrict__ Nb,
    const float* __restrict__ dwp)
{
    const int row = blockIdx.x;
    const int tid = threadIdx.x;
    const int h = tid >> 5, dh0 = (tid & 31) * 4;
    const int b = row >> 11, q = row & 2047;

    size_t ob = ((size_t)row * 8 + h) * 2 * 128;
    f32x4 a0 = *(const f32x4*)&Oacc[ob + dh0];
    f32x4 a1 = *(const f32x4*)&Oacc[ob + 128 + dh0];
    float l0 = Lacc[(size_t)((b * 8 + h) * 2 + 0) * SDIM + q];
    float l1 = Lacc[(size_t)((b * 8 + h) * 2 + 1) * SDIM + q];
    const float dw = dwp[0];
    float inv0 = 1.0f / l0;
    float inv1 = dw / l1;
    float o[4];
#pragma unroll
    for (int k = 0; k < 4; ++k) o[k] = a0[k] * inv0 - a1[k] * inv1;

    float ss = o[0] * o[0] + o[1] * o[1] + o[2] * o[2] + o[3] * o[3];
    ss += __shfl_xor(ss, 1,  64);
    ss += __shfl_xor(ss, 2,  64);
    ss += __shfl_xor(ss, 4,  64);
    ss += __shfl_xor(ss, 8,  64);
    ss += __shfl_xor(ss, 16, 64);
    ss += __shfl_xor(ss, 32, 64);
    __shared__ float red[4];
    if ((tid & 63) == 0) red[tid >> 6] = ss;
    __syncthreads();
    float tot = red[0] + red[1] + red[2] + red[3];
    float rms = rsqrtf(tot * (1.0f / 1024.0f) + 1.1920929e-07f);

    float4 w = *(const float4*)&nw[tid * 4];
    u16x4 pk;
    pk[0] = bf16rne(o[0] * rms * w.x);
    pk[1] = bf16rne(o[1] * rms * w.y);
    pk[2] = bf16rne(o[2] * rms * w.z);
    pk[3] = bf16rne(o[3] * rms * w.w);
    *(u16x4*)&Nb[(size_t)row * EDIM + tid * 4] = pk;
}

// ------------------------------------------------------------------
extern "C" void kernel_launch(void* const* d_in, const int* in_sizes, int n_in,
                              void* d_out, int out_size, void* d_ws, size_t ws_size,
                              hipStream_t stream)
{
    const float* x   = (const float*)d_in[0];
    const float* Wq  = (const float*)d_in[1];
    const float* Wk  = (const float*)d_in[2];
    const float* Wv  = (const float*)d_in[3];
    const float* nw  = (const float*)d_in[4];
    const float* Wo  = (const float*)d_in[5];
    const float* bo  = (const float*)d_in[6];
    const float* dwp = (const float*)d_in[7];
    float* out = (float*)d_out;

    float* Oacc = (float*)d_ws;                          // 32 MB
    u16*  xb   = (u16*)d_ws;                             // overlays Oacc head
    u16*  wob  = (u16*)((char*)d_ws + 33554432);         // 2 MB
    u16*  wqb  = wob + 1048576;
    u16*  wkb  = wqb + 1048576;
    u16*  wvb  = wkb + 1048576;
    float* Lacc = (float*)wqb;                           // overlays wqb (dead)
    u16*  Qb   = wvb + 1048576;                          // 8 MB
    u16*  Kb   = Qb + 4194304;
    u16*  Vtb  = Kb + 4194304;
    u16*  Nb   = Qb;                                     // overlays Qb (dead)

    cast_bf16<<<4096, 256, 0, stream>>>(x, Wq, Wk, Wv, Wo,
                                        xb, wqb, wkb, wvb, wob);
    gemm_qkv<<<dim3(GN / 128, GM / 128, 3), 256, 0, stream>>>(
        xb, wqb, wkb, wvb, Qb, Kb, Vtb);
    attn_mfma<<<dim3(SDIM / 128, 2 * HDIM, 2), 256, 0, stream>>>(
        Qb, Kb, Vtb, Oacc, Lacc);
    rms_combine<<<4096, 256, 0, stream>>>(Oacc, Lacc, nw, Nb, dwp);
    gemm_out<<<dim3(GN / 128, GM / 128, 1), 256, 0, stream>>>(
        Nb, wob, out, bo, dwp);
}

// Round 8
// 238.683 us; speedup vs baseline: 1.2333x; 1.0272x over previous
//
#include <hip/hip_runtime.h>
#include <hip/hip_bf16.h>
#include <math.h>

// MultiHeadDiffAttention, MI355X. Round 15: register-batched LDS reads.
// R14 post-mortem (93us, WIN -25%): stores/zero-tail/KVBLK=64 landed as
// predicted. Remaining: no pipe >50% (Mfma 23, VALU-true ~24, LDS ~25,
// HBM 14) but wall slot ~7000cyc vs ~2600 of demand -> exposed LDS-read
// latency. Evidence: VGPR_Count=76 -- allocator left ~180 regs unused, so
// the 40 LDS reads/wave-iter issue in small batches, each eating ~120cyc
// serially. 2 waves/SIMD can't hide it.
// R15: hoist ALL K frags (8 x bf16x8) and ALL V frags (16 x bf16x8) into
// registers before their MFMA clusters -> one batched latency wait per
// phase. ~170-190 arch VGPR + 64 acc, fine at 2 waves/SIMD (grid-limited).
// No layout/sync/numeric change; same MFMA order.
// Keeps: branch-split, full-kv/block, KVBLK=64, store epilogue (no atomics,
// no zero_ws), S^T scheme, in-register P pack, fused combine+RMSNorm.
// B=2 S=2048 E=1024 H=8 DH=128 F=64.
// ws layout (64 MB):
//   [Oacc 32MB f32 (xb bf16 overlays head; attn fully overwrites by STORE)]
//   [wob 2MB][wqb 2MB <- Lacc overlays after gemm_qkv][wkb 2][wvb 2]
//   [Qb 8MB <- Nb overlays after attn][Kb 8MB][Vtb 8MB]

#define SDIM 2048
#define EDIM 1024
#define HDIM 8
#define DHDIM 128

typedef unsigned short u16;
typedef __attribute__((ext_vector_type(8))) short bf16x8;
typedef __attribute__((ext_vector_type(4))) short bf16x4;
typedef __attribute__((ext_vector_type(4))) u16 u16x4;
typedef __attribute__((ext_vector_type(8))) u16 u16x8;
typedef __attribute__((ext_vector_type(4))) float f32x4;

__device__ __forceinline__ u16 bf16rne(float f) {
    unsigned int u = __float_as_uint(f);
    u += 0x7fff + ((u >> 16) & 1);
    return (u16)(u >> 16);
}

__device__ __forceinline__ void gload16(void* lds, const void* g) {
    __builtin_amdgcn_global_load_lds(
        (const __attribute__((address_space(1))) unsigned int*)g,
        (__attribute__((address_space(3))) unsigned int*)lds, 16, 0, 0);
}

constexpr int GM = 4096, GN = 1024, GK = 1024;

// ------------------------------------------------------------------
// cast fp32 -> bf16: x (4M) + Wq/Wk/Wv/Wo (1M each).
// ------------------------------------------------------------------
__global__ __launch_bounds__(256) void cast_bf16(
    const float* __restrict__ x,  const float* __restrict__ wq,
    const float* __restrict__ wk, const float* __restrict__ wv,
    const float* __restrict__ wo,
    u16* __restrict__ xb,  u16* __restrict__ wqb, u16* __restrict__ wkb,
    u16* __restrict__ wvb, u16* __restrict__ wob)
{
    int bid = blockIdx.x;
    const float* src; u16* dst; int lb;
    if (bid < 2048)      { src = x;  dst = xb;  lb = bid; }
    else if (bid < 2560) { src = wq; dst = wqb; lb = bid - 2048; }
    else if (bid < 3072) { src = wk; dst = wkb; lb = bid - 2560; }
    else if (bid < 3584) { src = wv; dst = wvb; lb = bid - 3072; }
    else                 { src = wo; dst = wob; lb = bid - 3584; }
    size_t i = ((size_t)lb * 256 + threadIdx.x) * 8;
    float4 a = *(const float4*)&src[i];
    float4 b = *(const float4*)&src[i + 4];
    u16x8 o;
    o[0] = bf16rne(a.x); o[1] = bf16rne(a.y); o[2] = bf16rne(a.z); o[3] = bf16rne(a.w);
    o[4] = bf16rne(b.x); o[5] = bf16rne(b.y); o[6] = bf16rne(b.z); o[7] = bf16rne(b.w);
    *(u16x8*)&dst[i] = o;
}

// ------------------------------------------------------------------
// bf16 MFMA GEMM core: C = A @ W^T, 128x128, BK=32. (unchanged)
// ------------------------------------------------------------------
struct GemmCore {
    f32x4 acc[4][4];
    int m0, n0, wm, wn, ln, quad;
};

__device__ __forceinline__ void gemm_core(
    GemmCore& g, const u16* __restrict__ A, const u16* __restrict__ W,
    u16* AsBase, u16* BsBase)
{
    const int tid = threadIdx.x;
    const int lane = tid & 63;
    const int wv = tid >> 6;
    g.ln = lane & 15; g.quad = lane >> 4;
    g.wm = (wv >> 1) * 64; g.wn = (wv & 1) * 64;
    g.m0 = blockIdx.y * 128; g.n0 = blockIdx.x * 128;

#pragma unroll
    for (int i = 0; i < 4; ++i)
#pragma unroll
        for (int j = 0; j < 4; ++j)
            g.acc[i][j] = (f32x4){0.f, 0.f, 0.f, 0.f};

    const int s0 = tid, s1 = tid + 256;
    const int ar0 = s0 >> 2, ac0 = (((s0 & 3) ^ ((ar0 >> 1) & 3)) * 8);
    const int ar1 = s1 >> 2, ac1 = (((s1 & 3) ^ ((ar1 >> 1) & 3)) * 8);
    const u16* pa0 = A + (size_t)(g.m0 + ar0) * GK + ac0;
    const u16* pa1 = A + (size_t)(g.m0 + ar1) * GK + ac1;
    const u16* pb0 = W + (size_t)(g.n0 + ar0) * GK + ac0;
    const u16* pb1 = W + (size_t)(g.n0 + ar1) * GK + ac1;
    u16* la0 = AsBase + s0 * 8; u16* la1 = AsBase + s1 * 8;
    u16* lb0 = BsBase + s0 * 8; u16* lb1 = BsBase + s1 * 8;

    const int roff = ((g.quad ^ ((g.ln >> 1) & 3)) * 8);

    for (int k0 = 0; k0 < GK; k0 += 32) {
        gload16(la0, pa0 + k0);
        gload16(la1, pa1 + k0);
        gload16(lb0, pb0 + k0);
        gload16(lb1, pb1 + k0);
        __syncthreads();

        bf16x8 af[4], bfr[4];
#pragma unroll
        for (int t = 0; t < 4; ++t) {
            af[t]  = *(const bf16x8*)&AsBase[(g.wm + t * 16 + g.ln) * 32 + roff];
            bfr[t] = *(const bf16x8*)&BsBase[(g.wn + t * 16 + g.ln) * 32 + roff];
        }
#pragma unroll
        for (int i = 0; i < 4; ++i)
#pragma unroll
            for (int j = 0; j < 4; ++j)
                g.acc[i][j] = __builtin_amdgcn_mfma_f32_16x16x32_bf16(
                    af[i], bfr[j], g.acc[i][j], 0, 0, 0);
        __syncthreads();
    }
}

// z=0 -> Qb (bf16, PRE-SCALED by 0.125*log2e), z=1 -> Kb, z=2 -> Vt
__global__ __launch_bounds__(256) void gemm_qkv(
    const u16* __restrict__ A,
    const u16* __restrict__ W0, const u16* __restrict__ W1, const u16* __restrict__ W2,
    u16* __restrict__ Qb, u16* __restrict__ Kb, u16* __restrict__ Vtb)
{
    __shared__ u16 As[128 * 32];
    __shared__ u16 Bs[128 * 32];
    const int z = blockIdx.z;
    const u16* W = (z == 0) ? W0 : ((z == 1) ? W1 : W2);
    GemmCore g;
    gemm_core(g, A, W, As, Bs);

    if (z < 2) {
        const float scl = (z == 0) ? 0.125f * 1.44269504f : 1.0f;
        u16* C = (z == 0) ? Qb : Kb;
#pragma unroll
        for (int i = 0; i < 4; ++i) {
            int rb = g.m0 + g.wm + i * 16 + g.quad * 4;
#pragma unroll
            for (int r = 0; r < 4; ++r) {
                u16* crow = C + (size_t)(rb + r) * GN + g.n0 + g.wn + g.ln;
#pragma unroll
                for (int j = 0; j < 4; ++j)
                    crow[j * 16] = bf16rne(g.acc[i][j][r] * scl);
            }
        }
    } else {
        const int bb = g.m0 >> 11;
        const int sb = (g.m0 & 2047) + g.wm + g.quad * 4;
#pragma unroll
        for (int j = 0; j < 4; ++j) {
            int dhg = g.n0 + g.wn + j * 16 + g.ln;
            int hh = dhg >> 7, dh = dhg & 127;
            u16* vrow = Vtb + ((size_t)(bb * 8 + hh) * DHDIM + dh) * SDIM + sb;
#pragma unroll
            for (int i = 0; i < 4; ++i) {
                u16x4 pk;
#pragma unroll
                for (int r = 0; r < 4; ++r) pk[r] = bf16rne(g.acc[i][j][r]);
                *(u16x4*)&vrow[i * 16] = pk;
            }
        }
    }
}

// out = (A @ W.T + bias) * (1-dw), fp32 output
__global__ __launch_bounds__(256) void gemm_out(
    const u16* __restrict__ A, const u16* __restrict__ W,
    float* __restrict__ C, const float* __restrict__ bias,
    const float* __restrict__ dwp)
{
    __shared__ u16 As[128 * 32];
    __shared__ u16 Bs[128 * 32];
    GemmCore g;
    gemm_core(g, A, W, As, Bs);

    const float scale = 1.0f - dwp[0];
    float bv[4];
#pragma unroll
    for (int j = 0; j < 4; ++j) bv[j] = bias[g.n0 + g.wn + j * 16 + g.ln];
#pragma unroll
    for (int i = 0; i < 4; ++i) {
        int rb = g.m0 + g.wm + i * 16 + g.quad * 4;
#pragma unroll
        for (int r = 0; r < 4; ++r) {
            float* crow = C + (size_t)(rb + r) * GN + g.n0 + g.wn + g.ln;
#pragma unroll
            for (int j = 0; j < 4; ++j)
                crow[j * 16] = (g.acc[i][j][r] + bv[j]) * scale;
        }
    }
}

// ------------------------------------------------------------------
// MFMA diff attention v12: R14 + register-batched LDS reads.
// Block = 4 waves; wave owns 32 q (2 q-tiles) for ONE branch.
// Grid (16 qt, 16 bh, 2 br) = 512 blocks = 2/CU, zero tail.
// 32 outer iters of 64 kv; dbuf 1-barrier staging.
// Per iter: batch-load kf[4][2] (8 x b128) -> S^T MFMAs; exp/pack;
// batch-load vf[8][2] (32 x b64) -> PV MFMAs. One latency wait per batch.
// ------------------------------------------------------------------
#define KBUF 4096   // u16 per K buffer (64 rows x 64 feats)
#define VBUF 8192   // u16 per V buffer (2 subs x 128 dh x 32 kv)

__global__ __launch_bounds__(256, 2) void attn_mfma(
    const u16* __restrict__ Qb, const u16* __restrict__ Kb,
    const u16* __restrict__ Vtb,
    float* __restrict__ Oacc, float* __restrict__ Lacc)
{
    __shared__ u16 Ks[2 * KBUF];
    __shared__ u16 Vs[2 * VBUF];

    const int tid = threadIdx.x;
    const int wv   = tid >> 6;
    const int lane = tid & 63;
    const int ln = lane & 15, quad = lane >> 4;
    const int lx = ln & 7;
    const int vkey = (ln >> 1) & 3;
    const int bh = blockIdx.y, b = bh >> 3, h = bh & 7;
    const int q0 = blockIdx.x * 128 + wv * 32;        // wave's 32 q rows
    const int BR = blockIdx.z;                        // branch 0/1

    // Q B-frags (pre-scaled): [qt][half], branch BR feats BR*64 + half*32 + quad*8
    const size_t qoff = (size_t)b * SDIM * EDIM + h * DHDIM + BR * 64;
    bf16x8 aq[2][2];
#pragma unroll
    for (int qt = 0; qt < 2; ++qt) {
        const u16* qp = Qb + qoff + (size_t)(q0 + qt * 16 + ln) * EDIM + quad * 8;
        aq[qt][0] = *(const bf16x8*)(qp);
        aq[qt][1] = *(const bf16x8*)(qp + 32);
    }

    // staging maps.
    // K: slot s (16B) -> row s>>3 (0..63), chunk ((s&7)^(row&7)) of 8.
    // V per 32-kv sub: slot s -> row s>>2 (0..127), chunk ((s&3)^((row>>1)&3)).
    const int s0 = tid, s1 = tid + 256;
    const int kr0 = s0 >> 3, kc0 = ((s0 & 7) ^ (kr0 & 7)) * 8;
    const int kr1 = s1 >> 3, kc1 = ((s1 & 7) ^ (kr1 & 7)) * 8;
    const u16* kg0 = Kb + (size_t)(b * SDIM + kr0) * EDIM + h * DHDIM + BR * 64 + kc0;
    const u16* kg1 = Kb + (size_t)(b * SDIM + kr1) * EDIM + h * DHDIM + BR * 64 + kc1;
    const int vr0 = s0 >> 2, vc0 = ((s0 & 3) ^ ((vr0 >> 1) & 3)) * 8;
    const int vr1 = s1 >> 2, vc1 = ((s1 & 3) ^ ((vr1 >> 1) & 3)) * 8;
    const u16* vg0 = Vtb + ((size_t)bh * DHDIM + vr0) * SDIM + vc0;
    const u16* vg1 = Vtb + ((size_t)bh * DHDIM + vr1) * SDIM + vc1;
    u16* ksd0 = Ks + s0 * 8; u16* ksd1 = Ks + s1 * 8;
    u16* vsd0 = Vs + s0 * 8; u16* vsd1 = Vs + s1 * 8;

    // prologue: stage iter 0 into buffer 0 (kv 0..63)
    gload16(ksd0, kg0); gload16(ksd1, kg1);
    gload16(vsd0, vg0); gload16(vsd1, vg1);
    gload16(vsd0 + 4096, vg0 + 32); gload16(vsd1 + 4096, vg1 + 32);
    kg0 += 64 * EDIM; kg1 += 64 * EDIM; vg0 += 64; vg1 += 64;

    f32x4 acc[2][8];                    // [qt][dt], one branch
#pragma unroll
    for (int qt = 0; qt < 2; ++qt)
#pragma unroll
        for (int d = 0; d < 8; ++d)
            acc[qt][d] = (f32x4){0.f, 0.f, 0.f, 0.f};
    float lsum[2] = {0.f, 0.f};
    const f32x4 z4 = (f32x4){0.f, 0.f, 0.f, 0.f};

    for (int it = 0; it < 32; ++it) {
        const int cur = it & 1;
        __syncthreads();   // buf[cur] loads complete; all waves done with buf[cur^1]

        if (it < 31) {     // prefetch iter it+1 into the other buffer
            const int kb = (cur ^ 1) * KBUF, vb2 = (cur ^ 1) * VBUF;
            gload16(ksd0 + kb, kg0); gload16(ksd1 + kb, kg1);
            gload16(vsd0 + vb2, vg0); gload16(vsd1 + vb2, vg1);
            gload16(vsd0 + vb2 + 4096, vg0 + 32); gload16(vsd1 + vb2 + 4096, vg1 + 32);
            kg0 += 64 * EDIM; kg1 += 64 * EDIM; vg0 += 64; vg1 += 64;
        }

        const u16* Kc = Ks + cur * KBUF;
        const u16* Vc = Vs + cur * VBUF;

        // ---- batch-load ALL K frags for this iter (8 x ds_read_b128) ----
        bf16x8 kf[4][2];
#pragma unroll
        for (int t2 = 0; t2 < 4; ++t2) {
            const int rb = (t2 * 16 + ln) * 64;
            kf[t2][0] = *(const bf16x8*)&Kc[rb + ((quad ^ lx) * 8)];
            kf[t2][1] = *(const bf16x8*)&Kc[rb + (((4 + quad) ^ lx) * 8)];
        }

        // ---- S^T over 64 kv: st[qt][t2] (MFMAs back-to-back) ----
        f32x4 st[2][4];
#pragma unroll
        for (int t2 = 0; t2 < 4; ++t2)
#pragma unroll
            for (int qt = 0; qt < 2; ++qt) {
                f32x4 s = __builtin_amdgcn_mfma_f32_16x16x32_bf16(kf[t2][0], aq[qt][0], z4, 0, 0, 0);
                st[qt][t2] = __builtin_amdgcn_mfma_f32_16x16x32_bf16(kf[t2][1], aq[qt][1], s, 0, 0, 0);
            }

        // ---- batch-load ALL V frags for this iter (32 x ds_read_b64) ----
        bf16x8 vf[8][2];
#pragma unroll
        for (int dt = 0; dt < 8; ++dt) {
            const int vb = (dt * 16 + ln) * 32;
#pragma unroll
            for (int ks = 0; ks < 2; ++ks) {
                const u16* Vk = Vc + ks * 4096;
                bf16x4 vlo = *(const bf16x4*)&Vk[vb + ((((quad >> 1) + 0) ^ vkey) * 8 + (quad & 1) * 4)];
                bf16x4 vhi = *(const bf16x4*)&Vk[vb + ((((quad >> 1) + 2) ^ vkey) * 8 + (quad & 1) * 4)];
                vf[dt][ks] = __builtin_shufflevector(vlo, vhi, 0, 1, 2, 3, 4, 5, 6, 7);
            }
        }

        // ---- exp + lsum + in-register pack: ap[qt][ks] (ks = kv-32-half) ----
        union { unsigned int u[4]; bf16x8 v; } ap[2][2];
#pragma unroll
        for (int qt = 0; qt < 2; ++qt)
#pragma unroll
            for (int ks = 0; ks < 2; ++ks) {
                float e0 = exp2f(st[qt][2 * ks][0]), e1 = exp2f(st[qt][2 * ks][1]);
                float e2 = exp2f(st[qt][2 * ks][2]), e3 = exp2f(st[qt][2 * ks][3]);
                float f0 = exp2f(st[qt][2 * ks + 1][0]), f1 = exp2f(st[qt][2 * ks + 1][1]);
                float f2 = exp2f(st[qt][2 * ks + 1][2]), f3 = exp2f(st[qt][2 * ks + 1][3]);
                lsum[qt] += (e0 + e1) + (e2 + e3) + (f0 + f1) + (f2 + f3);
                ap[qt][ks].u[0] = __builtin_amdgcn_perm(__float_as_uint(e1), __float_as_uint(e0), 0x07060302u);
                ap[qt][ks].u[1] = __builtin_amdgcn_perm(__float_as_uint(e3), __float_as_uint(e2), 0x07060302u);
                ap[qt][ks].u[2] = __builtin_amdgcn_perm(__float_as_uint(f1), __float_as_uint(f0), 0x07060302u);
                ap[qt][ks].u[3] = __builtin_amdgcn_perm(__float_as_uint(f3), __float_as_uint(f2), 0x07060302u);
            }

        // ---- PV: MFMAs back-to-back from registers ----
#pragma unroll
        for (int dt = 0; dt < 8; ++dt)
#pragma unroll
            for (int ks = 0; ks < 2; ++ks)
#pragma unroll
                for (int qt = 0; qt < 2; ++qt)
                    acc[qt][dt] = __builtin_amdgcn_mfma_f32_16x16x32_bf16(ap[qt][ks].v, vf[dt][ks], acc[qt][dt], 0, 0, 0);
    }

    // ---- epilogue: plain stores (sole writer of branch-BR slots) ----
#pragma unroll
    for (int qt = 0; qt < 2; ++qt) {
#pragma unroll
        for (int r = 0; r < 4; ++r) {
            size_t row = (size_t)(b * SDIM + q0 + qt * 16 + quad * 4 + r);
            float* o = Oacc + ((row * 8 + h) * 2 + BR) * 128 + ln;
#pragma unroll
            for (int dt = 0; dt < 8; ++dt)
                o[dt * 16] = acc[qt][dt][r];
        }
    }
    // ---- l: lane owns q=ln within tile; reduce across quads; store ----
#pragma unroll
    for (int qt = 0; qt < 2; ++qt) {
        float l = lsum[qt];
        l += __shfl_xor(l, 16, 64); l += __shfl_xor(l, 32, 64);
        if (quad == 0)
            Lacc[(size_t)((b * 8 + h) * 2 + BR) * SDIM + q0 + qt * 16 + ln] = l;
    }
}

// ------------------------------------------------------------------
// combine branches + RMSNorm -> bf16 normed. Grid 4096 rows x 256 thr.
// ------------------------------------------------------------------
__global__ __launch_bounds__(256) void rms_combine(
    const float* __restrict__ Oacc, const float* __restrict__ Lacc,
    const float* __restrict__ nw, u16* __restrict__ Nb,
    const float* __restrict__ dwp)
{
    const int row = blockIdx.x;
    const int tid = threadIdx.x;
    const int h = tid >> 5, dh0 = (tid & 31) * 4;
    const int b = row >> 11, q = row & 2047;

    size_t ob = ((size_t)row * 8 + h) * 2 * 128;
    f32x4 a0 = *(const f32x4*)&Oacc[ob + dh0];
    f32x4 a1 = *(const f32x4*)&Oacc[ob + 128 + dh0];
    float l0 = Lacc[(size_t)((b * 8 + h) * 2 + 0) * SDIM + q];
    float l1 = Lacc[(size_t)((b * 8 + h) * 2 + 1) * SDIM + q];
    const float dw = dwp[0];
    float inv0 = 1.0f / l0;
    float inv1 = dw / l1;
    float o[4];
#pragma unroll
    for (int k = 0; k < 4; ++k) o[k] = a0[k] * inv0 - a1[k] * inv1;

    float ss = o[0] * o[0] + o[1] * o[1] + o[2] * o[2] + o[3] * o[3];
    ss += __shfl_xor(ss, 1,  64);
    ss += __shfl_xor(ss, 2,  64);
    ss += __shfl_xor(ss, 4,  64);
    ss += __shfl_xor(ss, 8,  64);
    ss += __shfl_xor(ss, 16, 64);
    ss += __shfl_xor(ss, 32, 64);
    __shared__ float red[4];
    if ((tid & 63) == 0) red[tid >> 6] = ss;
    __syncthreads();
    float tot = red[0] + red[1] + red[2] + red[3];
    float rms = rsqrtf(tot * (1.0f / 1024.0f) + 1.1920929e-07f);

    float4 w = *(const float4*)&nw[tid * 4];
    u16x4 pk;
    pk[0] = bf16rne(o[0] * rms * w.x);
    pk[1] = bf16rne(o[1] * rms * w.y);
    pk[2] = bf16rne(o[2] * rms * w.z);
    pk[3] = bf16rne(o[3] * rms * w.w);
    *(u16x4*)&Nb[(size_t)row * EDIM + tid * 4] = pk;
}

// ------------------------------------------------------------------
extern "C" void kernel_launch(void* const* d_in, const int* in_sizes, int n_in,
                              void* d_out, int out_size, void* d_ws, size_t ws_size,
                              hipStream_t stream)
{
    const float* x   = (const float*)d_in[0];
    const float* Wq  = (const float*)d_in[1];
    const float* Wk  = (const float*)d_in[2];
    const float* Wv  = (const float*)d_in[3];
    const float* nw  = (const float*)d_in[4];
    const float* Wo  = (const float*)d_in[5];
    const float* bo  = (const float*)d_in[6];
    const float* dwp = (const float*)d_in[7];
    float* out = (float*)d_out;

    float* Oacc = (float*)d_ws;                          // 32 MB
    u16*  xb   = (u16*)d_ws;                             // overlays Oacc head
    u16*  wob  = (u16*)((char*)d_ws + 33554432);         // 2 MB
    u16*  wqb  = wob + 1048576;
    u16*  wkb  = wqb + 1048576;
    u16*  wvb  = wkb + 1048576;
    float* Lacc = (float*)wqb;                           // overlays wqb (dead)
    u16*  Qb   = wvb + 1048576;                          // 8 MB
    u16*  Kb   = Qb + 4194304;
    u16*  Vtb  = Kb + 4194304;
    u16*  Nb   = Qb;                                     // overlays Qb (dead)

    cast_bf16<<<4096, 256, 0, stream>>>(x, Wq, Wk, Wv, Wo,
                                        xb, wqb, wkb, wvb, wob);
    gemm_qkv<<<dim3(GN / 128, GM / 128, 3), 256, 0, stream>>>(
        xb, wqb, wkb, wvb, Qb, Kb, Vtb);
    attn_mfma<<<dim3(SDIM / 128, 2 * HDIM, 2), 256, 0, stream>>>(
        Qb, Kb, Vtb, Oacc, Lacc);
    rms_combine<<<4096, 256, 0, stream>>>(Oacc, Lacc, nw, Nb, dwp);
    gemm_out<<<dim3(GN / 128, GM / 128, 1), 256, 0, stream>>>(
        Nb, wob, out, bo, dwp);
}